// Round 14
// baseline (245.289 us; speedup 1.0000x reference)
//
#include <hip/hip_runtime.h>
#include <hip/hip_bf16.h>
#include <math.h>

#define T_LEN 4096
#define BATCH 16

typedef _Float16 f16;
typedef _Float16 f16x2 __attribute__((ext_vector_type(2)));
typedef _Float16 f16x8 __attribute__((ext_vector_type(8)));
typedef float f32x4 __attribute__((ext_vector_type(4)));

// Packed MFMA A-fragments, hi/lo split-f16. 136 logical frags:
// per layer (60): S[k(3)][q(2)]=0..5, M[k(5)][q(2)]=6..15,
// L[k(9)][q(2)][ms(2)]=16..51, O[ms(4)][kh(2)]=52..59; layer stride 60.
// D (dense 64->32): 120..123 = [ms(2)][kh(2)].
// GCN: 124..127 = bone proj A1[df]; 128..131 = palm proj A[df];
//      132..135 = bone proj A2[df].
// Frag f: hi at f*1024 + lane*8, lo at f*1024 + 512 + lane*8 (f16 units).
// k_mstcn uses HI halves only (pure-f16, R20); k_gcn uses hi+lo (3-MFMA).
__device__ __align__(16) f16 g_pk[136 * 1024];

// ---------------------------------------------------------------------------
// k_pack: one-time weight repack -> MFMA fragments (hi/lo f16). (unchanged)
// ---------------------------------------------------------------------------
__global__ void k_pack(
    const float* __restrict__ ws1, const float* __restrict__ wm1,
    const float* __restrict__ wl1, const float* __restrict__ wo1,
    const float* __restrict__ ws2, const float* __restrict__ wm2,
    const float* __restrict__ wl2, const float* __restrict__ wo2,
    const float* __restrict__ wd,  const float* __restrict__ gcn_w)
{
    const int g = blockIdx.x;          // 0..135 logical frag
    const int tid = threadIdx.x;
    #pragma unroll
    for (int u = 0; u < 2; ++u) {
        const int e = tid * 2 + u;     // 0..511
        const int lane = e >> 3, j = e & 7;
        const int m = lane & 15, k = (lane >> 4) * 8 + j;
        float w;
        if (g < 120) {
            const int layer = g / 60, r0 = g % 60;
            const float* pws = layer ? ws2 : ws1;
            const float* pwm = layer ? wm2 : wm1;
            const float* pwl = layer ? wl2 : wl1;
            const float* pwo = layer ? wo2 : wo1;
            if (r0 < 6) {
                const int kp = r0 >> 1, q = r0 & 1;
                w = pws[(kp * 64 + q * 32 + k) * 16 + m];        // ws[k][c][j]
            } else if (r0 < 16) {
                const int r = r0 - 6, kp = r >> 1, q = r & 1;
                w = pwm[(kp * 64 + q * 32 + k) * 16 + m];
            } else if (r0 < 52) {
                const int r = r0 - 16, kp = r >> 2, q = (r >> 1) & 1, ms = r & 1;
                w = pwl[(kp * 64 + q * 32 + k) * 32 + ms * 16 + m];
            } else {
                const int r = r0 - 52, ms = r >> 1, kh = r & 1;
                w = pwo[(kh * 32 + k) * 64 + ms * 16 + m];       // wo[j][d] -> A[d][j]
            }
        } else if (g < 124) {
            const int r = g - 120, ms = r >> 1, kh = r & 1;
            w = wd[(kh * 32 + k) * 32 + ms * 16 + m];            // wd[d][e] -> A[e][d]
        } else if (g < 132) {
            const int r = g - 124, df = r & 3;
            const int lim = (r >> 2) ? 18 : 10;                  // palm : bone A1
            w = (k < lim) ? gcn_w[k * 64 + df * 16 + m] : 0.f;
        } else {
            const int df = (g - 132) & 3;                        // bone A2
            w = (k >= 10 && k < 20) ? gcn_w[(k - 10) * 64 + df * 16 + m] : 0.f;
        }
        const f16 hi = (f16)w;
        const f16 lo = (f16)(w - (float)hi);
        g_pk[g * 1024 + e] = hi;
        g_pk[g * 1024 + 512 + e] = lo;
    }
}

__device__ inline f32x4 mfma3z(f16x8 ah, f16x8 al, f16x8 bh, f16x8 bl) {
    f32x4 a = {0.f, 0.f, 0.f, 0.f};
    a = __builtin_amdgcn_mfma_f32_16x16x32_f16(ah, bh, a, 0, 0, 0);
    a = __builtin_amdgcn_mfma_f32_16x16x32_f16(ah, bl, a, 0, 0, 0);
    a = __builtin_amdgcn_mfma_f32_16x16x32_f16(al, bh, a, 0, 0, 0);
    return a;
}

// ---------------------------------------------------------------------------
// k_gcn R21: two-phase load batching (ILP for the x reads).
// R16/R19 invariance analysis: dur insensitive to load count, VALU count,
// occupancy — but ALL variants had `#pragma unroll 1` on the pair loop, so
// each pair's load->cvt->MFMA chain serialized ~10 exposed L1/L2 round
// trips (~2000+cy/thread). ILP-via-hoisted-global-loads is the only
// mechanism that has worked every time (R8 weights, R16 pk frags) and the
// only one never applied to k_gcn's x reads. R21: two batches of 5 pairs;
// phase 1 issues ALL the batch's loads into statically-indexed regs
// (full unroll, literal base -> (p&1) folds), phase 2 cvt+MFMA+chain.
// __launch_bounds__(256,2) lifts the VGPR cap (R15 lesson).
// Falsifier (pre-committed): dur >= 42us -> latency wasn't the stall ->
// TA-scatter-bound -> transpose pre-pass or declare roofline.
// ---------------------------------------------------------------------------
__global__ __launch_bounds__(256, 2) void k_gcn(
    const float* __restrict__ x,      // [B][T][218]
    float* __restrict__ hp)           // [B][64][T]
{
    const int b   = blockIdx.y;
    const int t0  = blockIdx.x * 64;
    const int tid = threadIdx.x;
    const int lane = tid & 63, wid = tid >> 6;
    const int l15 = lane & 15, lg = lane >> 4;
    const int t = t0 + wid * 16 + l15;
    const float* xrow = x + ((long)b * T_LEN + t) * 218;
    const int la8 = lane * 8;

    const float cP = 1.0f / 6.0f;
    const float cS = 0.23570226039551584f;   // 1/sqrt(18)
    const float c3 = 1.0f / 3.0f;
    const float cT = 0.4082482904638631f;    // 1/sqrt(6)
    const float cH = 0.5f;

    // ---- palm: h0 = x[0:18] . gcn_w  (K-pad lanes ch16..23, A=0 kills) ----
    f32x4 h0[4];
    {
        float vv[8];
        const int po = (lg < 2) ? lg * 8 : 16;
        *(float2*)(vv + 0) = *(const float2*)(xrow + po);
        *(float2*)(vv + 2) = *(const float2*)(xrow + po + 2);
        *(float2*)(vv + 4) = *(const float2*)(xrow + po + 4);
        *(float2*)(vv + 6) = *(const float2*)(xrow + po + 6);
        f16x8 bh, bl;
        #pragma unroll
        for (int j = 0; j < 8; ++j) {
            const f16 h = (f16)vv[j];
            bh[j] = h; bl[j] = (f16)(vv[j] - (float)h);
        }
        #pragma unroll
        for (int df = 0; df < 4; ++df) {
            const f16x8 ah = *(const f16x8*)(g_pk + (128 + df) * 1024 + la8);
            const f16x8 al = *(const f16x8*)(g_pk + (128 + df) * 1024 + 512 + la8);
            h0[df] = mfma3z(ah, al, bh, bl);
        }
    }

    // ---- bone-pair A-frags: register-resident, shared by all 10 pairs ----
    f16x8 A1h[4], A1l[4], A2h[4], A2l[4];
    #pragma unroll
    for (int df = 0; df < 4; ++df) {
        A1h[df] = *(const f16x8*)(g_pk + (124 + df) * 1024 + la8);
        A1l[df] = *(const f16x8*)(g_pk + (124 + df) * 1024 + 512 + la8);
        A2h[df] = *(const f16x8*)(g_pk + (132 + df) * 1024 + la8);
        A2l[df] = *(const f16x8*)(g_pk + (132 + df) * 1024 + 512 + la8);
    }

    f32x4 pool[4], star[4], s12[4], hprev[4];
    #pragma unroll
    for (int df = 0; df < 4; ++df) {
        pool[df] = (f32x4){0.f, 0.f, 0.f, 0.f};
        star[df] = (f32x4){0.f, 0.f, 0.f, 0.f};
    }

    // ---- bone pairs, two batches of 5: phase-1 load all, phase-2 chain ----
    // pair p covers bones (2p, 2p+1); ch [18+20p, 18+20p+20)
#define BATCH5(P0) do {                                                    \
        float vv[5][8];                                                    \
        _Pragma("unroll")                                                  \
        for (int i = 0; i < 5; ++i) {                                      \
            const float* bp = xrow + 18 + 20 * ((P0) + i);                 \
            if (lg < 2) {                                                  \
                const float* q = bp + lg * 8;                              \
                *(float2*)(vv[i] + 0) = *(const float2*)(q);               \
                *(float2*)(vv[i] + 2) = *(const float2*)(q + 2);           \
                *(float2*)(vv[i] + 4) = *(const float2*)(q + 4);           \
                *(float2*)(vv[i] + 6) = *(const float2*)(q + 6);           \
            } else if (lg == 2) {                                          \
                *(float2*)(vv[i] + 0) = *(const float2*)(bp + 16);         \
                *(float2*)(vv[i] + 2) = *(const float2*)(bp + 18);         \
                vv[i][4] = vv[i][5] = vv[i][6] = vv[i][7] = 0.f;           \
            } else {                                                       \
                _Pragma("unroll")                                          \
                for (int j = 0; j < 8; ++j) vv[i][j] = 0.f;                \
            }                                                              \
        }                                                                  \
        _Pragma("unroll")                                                  \
        for (int i = 0; i < 5; ++i) {                                      \
            const int p = (P0) + i;       /* literal after unroll */       \
            f16x8 bh, bl;                                                  \
            _Pragma("unroll")                                              \
            for (int j = 0; j < 8; ++j) {                                  \
                const f16 h = (f16)vv[i][j];                               \
                bh[j] = h; bl[j] = (f16)(vv[i][j] - (float)h);             \
            }                                                              \
            f32x4 hnA[4], hnB[4];                                          \
            _Pragma("unroll")                                              \
            for (int df = 0; df < 4; ++df) {                               \
                hnA[df] = mfma3z(A1h[df], A1l[df], bh, bl);                \
                hnB[df] = mfma3z(A2h[df], A2l[df], bh, bl);                \
            }                                                              \
            if ((p & 1) == 0) {                                            \
                _Pragma("unroll")                                          \
                for (int df = 0; df < 4; ++df)                             \
                    _Pragma("unroll")                                      \
                    for (int ii = 0; ii < 4; ++ii) {                       \
                        const float hA = hnA[df][ii], hB = hnB[df][ii];    \
                        star[df][ii] += hA;                                \
                        const float pa =                                   \
                            fmaf(cS, h0[df][ii], c3 * (hA + hB));          \
                        pool[df][ii] += fmaxf(pa, 0.f);                    \
                        s12[df][ii] = hA + hB;                             \
                        hprev[df][ii] = hB;                                \
                    }                                                      \
            } else {                                                       \
                _Pragma("unroll")                                          \
                for (int df = 0; df < 4; ++df)                             \
                    _Pragma("unroll")                                      \
                    for (int ii = 0; ii < 4; ++ii) {                       \
                        const float hA = hnA[df][ii], hB = hnB[df][ii];    \
                        const float pb = c3 * (s12[df][ii] + hA);          \
                        pool[df][ii] += fmaxf(pb, 0.f);                    \
                        const float s2 = hprev[df][ii] + hA;               \
                        const float pc = fmaf(cT, hB, c3 * s2);            \
                        const float pe = fmaf(cT, hA, cH * hB);            \
                        pool[df][ii] += fmaxf(pc, 0.f) + fmaxf(pe, 0.f);   \
                    }                                                      \
            }                                                              \
        }                                                                  \
    } while (0)

    BATCH5(0);
    BATCH5(5);
#undef BATCH5

    float* hpb = hp + (long)b * 64 * T_LEN + t;
    #pragma unroll
    for (int df = 0; df < 4; ++df)
        #pragma unroll
        for (int i = 0; i < 4; ++i) {
            const float p0 = fmaf(cP, h0[df][i], cS * star[df][i]);
            hpb[(long)(df * 16 + lg * 4 + i) * T_LEN] =
                (pool[df][i] + fmaxf(p0, 0.f)) * (1.0f / 21.0f);
        }
}

// ---------------------------------------------------------------------------
// k_mstcn R20: PURE-F16 (1 MFMA per logical product). (unchanged — passed
// at absmax 1.5e-5, ~<43us each)
// ---------------------------------------------------------------------------
template <bool FINAL>
__global__ __launch_bounds__(512, 4) void k_mstcn(
    const float* __restrict__ in,   // [B][64][T]
    const float* __restrict__ bs, const float* __restrict__ bm,
    const float* __restrict__ bl, const float* __restrict__ bo,
    int pkoff,                      // layer * 61440 (f16 units)
    float* __restrict__ out,        // [B][64][T]  (FINAL=false)
    const float* __restrict__ bd,   // [32]        (FINAL=true)
    float* __restrict__ outp)       // [B][32]     (FINAL=true)
{
    __shared__ __align__(16) f16 lds[25600];   // 51200 B

    const int b   = blockIdx.y;
    const int t0  = blockIdx.x * 128;
    const int tid = threadIdx.x;
    const float* inb = in + (long)b * 64 * T_LEN;

    // ---- stage x [t0-32, t0+128) -> transposed f16 plane (linear) ----
    {
        const int c0 = (tid >> 4) * 2;      // channel pair 0..62
        const int tq = (tid & 15) * 10;     // 10 rows per thread
        float v0[10], v1[10];
        if (t0 != 0 || tq >= 40) {
            const float* r0 = inb + (long)c0 * T_LEN + (t0 - 32 + tq);
            const float* r1 = r0 + T_LEN;
            #pragma unroll
            for (int m = 0; m < 5; ++m) {
                *(float2*)(v0 + 2 * m) = *(const float2*)(r0 + 2 * m);
                *(float2*)(v1 + 2 * m) = *(const float2*)(r1 + 2 * m);
            }
        } else {
            #pragma unroll
            for (int i = 0; i < 10; ++i) {
                const int tg_ = tq + i - 32;
                v0[i] = (tg_ >= 0) ? inb[(long)c0 * T_LEN + tg_] : 0.f;
                v1[i] = (tg_ >= 0) ? inb[(long)(c0 + 1) * T_LEN + tg_] : 0.f;
            }
        }
        #pragma unroll
        for (int i = 0; i < 10; ++i) {
            const int row = tq + i;
            *(f16x2*)(&lds[row * 72 + c0]) = (f16x2){(f16)v0[i], (f16)v1[i]};
        }
    }
    __syncthreads();                         // b1

    const int lane = tid & 63, wid = tid >> 6;
    const int qh  = wid >> 2;                // channel half (K-split)
    const int tg  = wid & 3;                 // t-group (32 t each)
    const int l15 = lane & 15, lg = lane >> 4;
    const int tws0 = tg * 32, tws1 = tg * 32 + 16;
    const f16* pk = g_pk + pkoff;
    const int la8 = lane * 8;

#define MFMA1(ACC, AH, BH)                                                 \
        ACC = __builtin_amdgcn_mfma_f32_16x16x32_f16(AH, BH, ACC, 0, 0, 0)

#define LOADA(AH, FR) AH = *(const f16x8*)(pk + (FR) * 1024 + la8)

#define BRD(BH, ROW) BH = *(const f16x8*)(&lds[(ROW) * 72 + qh * 32 + lg * 8])

    // ---- GEMM1: branches, channel-half qh, 2 t-subtiles. C[j][t] ----
    f32x4 aS0 = {0.f,0.f,0.f,0.f}, aS1 = {0.f,0.f,0.f,0.f};
    f32x4 aM0 = {0.f,0.f,0.f,0.f}, aM1 = {0.f,0.f,0.f,0.f};
    f32x4 aL00 = {0.f,0.f,0.f,0.f}, aL01 = {0.f,0.f,0.f,0.f};
    f32x4 aL10 = {0.f,0.f,0.f,0.f}, aL11 = {0.f,0.f,0.f,0.f};

    #pragma unroll
    for (int kp = 0; kp < 3; ++kp) {
        f16x8 ah, bh;
        LOADA(ah, 2 * kp + qh);
        BRD(bh, 30 + tws0 + l15 + kp); MFMA1(aS0, ah, bh);
        BRD(bh, 30 + tws1 + l15 + kp); MFMA1(aS1, ah, bh);
    }
    #pragma unroll
    for (int kp = 0; kp < 5; ++kp) {
        f16x8 ah, bh;
        LOADA(ah, 6 + 2 * kp + qh);
        BRD(bh, 24 + tws0 + l15 + 2 * kp); MFMA1(aM0, ah, bh);
        BRD(bh, 24 + tws1 + l15 + 2 * kp); MFMA1(aM1, ah, bh);
    }
    #pragma unroll
    for (int kp = 0; kp < 9; ++kp) {
        f16x8 a0h, a1h, bh;
        LOADA(a0h, 16 + 4 * kp + 2 * qh);
        LOADA(a1h, 16 + 4 * kp + 2 * qh + 1);
        BRD(bh, tws0 + l15 + 4 * kp);
        MFMA1(aL00, a0h, bh); MFMA1(aL10, a1h, bh);
        BRD(bh, tws1 + l15 + 4 * kp);
        MFMA1(aL01, a0h, bh); MFMA1(aL11, a1h, bh);
    }

    __syncthreads();                         // b2: X dead, RED live
    {
        float* red = (float*)lds;
        const int ro = (tg * 64 + lane) * 4; // 16B lane stride: conflict-free
        if (qh == 0) {
            *(f32x4*)(red + 0 * 1024 + ro) = aS0;
            *(f32x4*)(red + 1 * 1024 + ro) = aM0;
            *(f32x4*)(red + 2 * 1024 + ro) = aL00;
            *(f32x4*)(red + 3 * 1024 + ro) = aL10;
            *(f32x4*)(red + 4 * 1024 + ro) = aS1;
            *(f32x4*)(red + 5 * 1024 + ro) = aM1;
            *(f32x4*)(red + 6 * 1024 + ro) = aL01;
            *(f32x4*)(red + 7 * 1024 + ro) = aL11;
        }
        __syncthreads();                     // b3: last barrier (qh0 exits)
        if (qh == 0) return;
        aS0  += *(const f32x4*)(red + 0 * 1024 + ro);
        aM0  += *(const f32x4*)(red + 1 * 1024 + ro);
        aL00 += *(const f32x4*)(red + 2 * 1024 + ro);
        aL10 += *(const f32x4*)(red + 3 * 1024 + ro);
        aS1  += *(const f32x4*)(red + 4 * 1024 + ro);
        aM1  += *(const f32x4*)(red + 5 * 1024 + ro);
        aL01 += *(const f32x4*)(red + 6 * 1024 + ro);
        aL11 += *(const f32x4*)(red + 7 * 1024 + ro);
    }

    // ---- bias (+relu) + f16 stage into HH plane [t][j] (linear) ----
#define STAGEH(ACC, BPTR, JB, RELU, RB) do {                               \
        const float4 bv_ = *(const float4*)(BPTR);                         \
        float x0_ = ACC[0] + bv_.x, x1_ = ACC[1] + bv_.y,                  \
              x2_ = ACC[2] + bv_.z, x3_ = ACC[3] + bv_.w;                  \
        if (RELU) { x0_ = fmaxf(x0_, 0.f); x1_ = fmaxf(x1_, 0.f);          \
                    x2_ = fmaxf(x2_, 0.f); x3_ = fmaxf(x3_, 0.f); }        \
        const int ro_ = ((RB) + l15) * 72 + (JB) + lg * 4;                 \
        *(f16x2*)(&lds[16384 + ro_])     = (f16x2){(f16)x0_, (f16)x1_};    \
        *(f16x2*)(&lds[16384 + ro_ + 2]) = (f16x2){(f16)x2_, (f16)x3_};    \
    } while (0)

    STAGEH(aS0,  bs + lg * 4,       0,  true, tws0);
    STAGEH(aM0,  bm + lg * 4,       16, true, tws0);
    STAGEH(aL00, bl + lg * 4,       32, true, tws0);
    STAGEH(aL10, bl + 16 + lg * 4,  48, true, tws0);
    STAGEH(aS1,  bs + lg * 4,       0,  true, tws1);
    STAGEH(aM1,  bm + lg * 4,       16, true, tws1);
    STAGEH(aL01, bl + lg * 4,       32, true, tws1);
    STAGEH(aL11, bl + 16 + lg * 4,  48, true, tws1);
    // no barrier: wave reads only its own 32 H rows below

#define HRD(BH, RB, KH)                                                    \
        BH = *(const f16x8*)(&lds[16384 + ((RB) + l15) * 72 + (KH) * 32 + lg * 8])

    // ---- GEMM2: conv_out 64->64.  C[d][t], 2 subtiles ----
    f32x4 oA0 = {0.f,0.f,0.f,0.f}, oA1 = {0.f,0.f,0.f,0.f};
    f32x4 oA2 = {0.f,0.f,0.f,0.f}, oA3 = {0.f,0.f,0.f,0.f};
    f32x4 oB0 = {0.f,0.f,0.f,0.f}, oB1 = {0.f,0.f,0.f,0.f};
    f32x4 oB2 = {0.f,0.f,0.f,0.f}, oB3 = {0.f,0.f,0.f,0.f};
    #pragma unroll
    for (int kh = 0; kh < 2; ++kh) {
        f16x8 b0h, b1h, ah;
        HRD(b0h, tws0, kh);
        HRD(b1h, tws1, kh);
        LOADA(ah, 52 + 0 + kh); MFMA1(oA0, ah, b0h); MFMA1(oB0, ah, b1h);
        LOADA(ah, 52 + 2 + kh); MFMA1(oA1, ah, b0h); MFMA1(oB1, ah, b1h);
        LOADA(ah, 52 + 4 + kh); MFMA1(oA2, ah, b0h); MFMA1(oB2, ah, b1h);
        LOADA(ah, 52 + 6 + kh); MFMA1(oA3, ah, b0h); MFMA1(oB3, ah, b1h);
    }

    if (!FINAL) {
        const float4 b0v = *(const float4*)(bo + lg * 4);
        const float4 b1v = *(const float4*)(bo + 16 + lg * 4);
        const float4 b2v = *(const float4*)(bo + 32 + lg * 4);
        const float4 b3v = *(const float4*)(bo + 48 + lg * 4);
#define STO4(ACC, BV, MS, OB) do {                                         \
        (OB)[((MS) * 16 + lg * 4 + 0) * (long)T_LEN] = ACC[0] + BV.x;      \
        (OB)[((MS) * 16 + lg * 4 + 1) * (long)T_LEN] = ACC[1] + BV.y;      \
        (OB)[((MS) * 16 + lg * 4 + 2) * (long)T_LEN] = ACC[2] + BV.z;      \
        (OB)[((MS) * 16 + lg * 4 + 3) * (long)T_LEN] = ACC[3] + BV.w;      \
    } while (0)
        float* obA = out + (long)b * 64 * T_LEN + t0 + tws0 + l15;
        float* obB = out + (long)b * 64 * T_LEN + t0 + tws1 + l15;
        STO4(oA0, b0v, 0, obA); STO4(oB0, b0v, 0, obB);
        STO4(oA1, b1v, 1, obA); STO4(oB1, b1v, 1, obB);
        STO4(oA2, b2v, 2, obA); STO4(oB2, b2v, 2, obB);
        STO4(oA3, b3v, 3, obA); STO4(oB3, b3v, 3, obB);
#undef STO4
    } else {
        // ---- stage t2 (conv_out + bo, no relu); wave-local rows ----
        STAGEH(oA0, bo + lg * 4,       0,  false, tws0);
        STAGEH(oA1, bo + 16 + lg * 4,  16, false, tws0);
        STAGEH(oA2, bo + 32 + lg * 4,  32, false, tws0);
        STAGEH(oA3, bo + 48 + lg * 4,  48, false, tws0);
        STAGEH(oB0, bo + lg * 4,       0,  false, tws1);
        STAGEH(oB1, bo + 16 + lg * 4,  16, false, tws1);
        STAGEH(oB2, bo + 32 + lg * 4,  32, false, tws1);
        STAGEH(oB3, bo + 48 + lg * 4,  48, false, tws1);

        // ---- GEMM3: dense 64->32.  C[e][t], 2 subtiles ----
        f32x4 eA0 = {0.f,0.f,0.f,0.f}, eA1 = {0.f,0.f,0.f,0.f};
        f32x4 eB0 = {0.f,0.f,0.f,0.f}, eB1 = {0.f,0.f,0.f,0.f};
        #pragma unroll
        for (int kh = 0; kh < 2; ++kh) {
            f16x8 b0h, b1h, ah;
            HRD(b0h, tws0, kh);
            HRD(b1h, tws1, kh);
            ah = *(const f16x8*)(g_pk + (120 + 0 + kh) * 1024 + la8);
            MFMA1(eA0, ah, b0h); MFMA1(eB0, ah, b1h);
            ah = *(const f16x8*)(g_pk + (120 + 2 + kh) * 1024 + la8);
            MFMA1(eA1, ah, b0h); MFMA1(eB1, ah, b1h);
        }
        const float4 bd0 = *(const float4*)(bd + lg * 4);
        const float4 bd1 = *(const float4*)(bd + 16 + lg * 4);
        const float cI = 1.0f / (float)T_LEN;
        float u0 = (tanhf(eA0[0] + bd0.x) + tanhf(eB0[0] + bd0.x)) * cI;
        float u1 = (tanhf(eA0[1] + bd0.y) + tanhf(eB0[1] + bd0.y)) * cI;
        float u2 = (tanhf(eA0[2] + bd0.z) + tanhf(eB0[2] + bd0.z)) * cI;
        float u3 = (tanhf(eA0[3] + bd0.w) + tanhf(eB0[3] + bd0.w)) * cI;
        float u4 = (tanhf(eA1[0] + bd1.x) + tanhf(eB1[0] + bd1.x)) * cI;
        float u5 = (tanhf(eA1[1] + bd1.y) + tanhf(eB1[1] + bd1.y)) * cI;
        float u6 = (tanhf(eA1[2] + bd1.z) + tanhf(eB1[2] + bd1.z)) * cI;
        float u7 = (tanhf(eA1[3] + bd1.w) + tanhf(eB1[3] + bd1.w)) * cI;
#define RED(U) do { U += __shfl_xor(U, 1); U += __shfl_xor(U, 2);          \
                    U += __shfl_xor(U, 4); U += __shfl_xor(U, 8); } while (0)
        RED(u0); RED(u1); RED(u2); RED(u3);
        RED(u4); RED(u5); RED(u6); RED(u7);
#undef RED
        if (l15 == 0) {
            float* op = outp + b * 32;
            atomicAdd(op + lg * 4 + 0, u0);
            atomicAdd(op + lg * 4 + 1, u1);
            atomicAdd(op + lg * 4 + 2, u2);
            atomicAdd(op + lg * 4 + 3, u3);
            atomicAdd(op + 16 + lg * 4 + 0, u4);
            atomicAdd(op + 16 + lg * 4 + 1, u5);
            atomicAdd(op + 16 + lg * 4 + 2, u6);
            atomicAdd(op + 16 + lg * 4 + 3, u7);
        }
    }
#undef HRD
#undef STAGEH
#undef BRD
#undef LOADA
#undef MFMA1
}

extern "C" void kernel_launch(void* const* d_in, const int* in_sizes, int n_in,
                              void* d_out, int out_size, void* d_ws, size_t ws_size,
                              hipStream_t stream) {
    const float* x     = (const float*)d_in[0];
    const float* gcn_w = (const float*)d_in[1];
    const float* wd    = (const float*)d_in[2];
    const float* bd    = (const float*)d_in[3];
    const float* t1_ws = (const float*)d_in[4];
    const float* t1_bs = (const float*)d_in[5];
    const float* t1_wm = (const float*)d_in[6];
    const float* t1_bm = (const float*)d_in[7];
    const float* t1_wl = (const float*)d_in[8];
    const float* t1_bl = (const float*)d_in[9];
    const float* t1_wo = (const float*)d_in[10];
    const float* t1_bo = (const float*)d_in[11];
    const float* t2_ws = (const float*)d_in[12];
    const float* t2_bs = (const float*)d_in[13];
    const float* t2_wm = (const float*)d_in[14];
    const float* t2_bm = (const float*)d_in[15];
    const float* t2_wl = (const float*)d_in[16];
    const float* t2_bl = (const float*)d_in[17];
    const float* t2_wo = (const float*)d_in[18];
    const float* t2_bo = (const float*)d_in[19];

    float* b0 = (float*)d_ws;                          // [16][64][4096]
    float* b1 = b0 + (size_t)BATCH * 64 * T_LEN;       // [16][64][4096]

    hipMemsetAsync(d_out, 0, (size_t)out_size * sizeof(float), stream);

    k_pack<<<dim3(136), 256, 0, stream>>>(
        t1_ws, t1_wm, t1_wl, t1_wo, t2_ws, t2_wm, t2_wl, t2_wo, wd, gcn_w);

    k_gcn<<<dim3(T_LEN / 64, BATCH), 256, 0, stream>>>(x, b0);

    k_mstcn<false><<<dim3(T_LEN / 128, BATCH), 512, 0, stream>>>(
        b0, t1_bs, t1_bm, t1_bl, t1_bo, 0,
        b1, nullptr, nullptr);

    k_mstcn<true><<<dim3(T_LEN / 128, BATCH), 512, 0, stream>>>(
        b1, t2_bs, t2_bm, t2_bl, t2_bo, 61440,
        nullptr, bd, (float*)d_out);
}

// Round 15
// 201.675 us; speedup vs baseline: 1.2163x; 1.2163x over previous
//
#include <hip/hip_runtime.h>
#include <hip/hip_bf16.h>
#include <math.h>

#define T_LEN 4096
#define BATCH 16

typedef _Float16 f16;
typedef _Float16 f16x2 __attribute__((ext_vector_type(2)));
typedef _Float16 f16x8 __attribute__((ext_vector_type(8)));
typedef float f32x4 __attribute__((ext_vector_type(4)));

// Packed MFMA A-fragments, hi/lo split-f16. 136 logical frags:
// per layer (60): S[k(3)][q(2)]=0..5, M[k(5)][q(2)]=6..15,
// L[k(9)][q(2)][ms(2)]=16..51, O[ms(4)][kh(2)]=52..59; layer stride 60.
// D (dense 64->32): 120..123 = [ms(2)][kh(2)].
// GCN: 124..127 = bone proj A1[df]; 128..131 = palm proj A[df];
//      132..135 = bone proj A2[df].
// Frag f: hi at f*1024 + lane*8, lo at f*1024 + 512 + lane*8 (f16 units).
// k_mstcn uses HI halves only (pure-f16, R20); k_gcn uses hi+lo (3-MFMA).
__device__ __align__(16) f16 g_pk[136 * 1024];

// ---------------------------------------------------------------------------
// k_pack: one-time weight repack -> MFMA fragments (hi/lo f16). (unchanged)
// ---------------------------------------------------------------------------
__global__ void k_pack(
    const float* __restrict__ ws1, const float* __restrict__ wm1,
    const float* __restrict__ wl1, const float* __restrict__ wo1,
    const float* __restrict__ ws2, const float* __restrict__ wm2,
    const float* __restrict__ wl2, const float* __restrict__ wo2,
    const float* __restrict__ wd,  const float* __restrict__ gcn_w)
{
    const int g = blockIdx.x;          // 0..135 logical frag
    const int tid = threadIdx.x;
    #pragma unroll
    for (int u = 0; u < 2; ++u) {
        const int e = tid * 2 + u;     // 0..511
        const int lane = e >> 3, j = e & 7;
        const int m = lane & 15, k = (lane >> 4) * 8 + j;
        float w;
        if (g < 120) {
            const int layer = g / 60, r0 = g % 60;
            const float* pws = layer ? ws2 : ws1;
            const float* pwm = layer ? wm2 : wm1;
            const float* pwl = layer ? wl2 : wl1;
            const float* pwo = layer ? wo2 : wo1;
            if (r0 < 6) {
                const int kp = r0 >> 1, q = r0 & 1;
                w = pws[(kp * 64 + q * 32 + k) * 16 + m];        // ws[k][c][j]
            } else if (r0 < 16) {
                const int r = r0 - 6, kp = r >> 1, q = r & 1;
                w = pwm[(kp * 64 + q * 32 + k) * 16 + m];
            } else if (r0 < 52) {
                const int r = r0 - 16, kp = r >> 2, q = (r >> 1) & 1, ms = r & 1;
                w = pwl[(kp * 64 + q * 32 + k) * 32 + ms * 16 + m];
            } else {
                const int r = r0 - 52, ms = r >> 1, kh = r & 1;
                w = pwo[(kh * 32 + k) * 64 + ms * 16 + m];       // wo[j][d] -> A[d][j]
            }
        } else if (g < 124) {
            const int r = g - 120, ms = r >> 1, kh = r & 1;
            w = wd[(kh * 32 + k) * 32 + ms * 16 + m];            // wd[d][e] -> A[e][d]
        } else if (g < 132) {
            const int r = g - 124, df = r & 3;
            const int lim = (r >> 2) ? 18 : 10;                  // palm : bone A1
            w = (k < lim) ? gcn_w[k * 64 + df * 16 + m] : 0.f;
        } else {
            const int df = (g - 132) & 3;                        // bone A2
            w = (k >= 10 && k < 20) ? gcn_w[(k - 10) * 64 + df * 16 + m] : 0.f;
        }
        const f16 hi = (f16)w;
        const f16 lo = (f16)(w - (float)hi);
        g_pk[g * 1024 + e] = hi;
        g_pk[g * 1024 + 512 + e] = lo;
    }
}

__device__ inline f32x4 mfma3z(f16x8 ah, f16x8 al, f16x8 bh, f16x8 bl) {
    f32x4 a = {0.f, 0.f, 0.f, 0.f};
    a = __builtin_amdgcn_mfma_f32_16x16x32_f16(ah, bh, a, 0, 0, 0);
    a = __builtin_amdgcn_mfma_f32_16x16x32_f16(ah, bl, a, 0, 0, 0);
    a = __builtin_amdgcn_mfma_f32_16x16x32_f16(al, bh, a, 0, 0, 0);
    return a;
}

// ---------------------------------------------------------------------------
// k_gcn R22: R19 structure, FULL UNROLL of the pair loop.
// R21 post-mortem: hand-batched 5-pair prefetch (vv[5][8] = 40 f32 live)
// spilled catastrophically — WRITE_SIZE 16->195MB, FETCH 29->124MB
// (~300MB scratch), dur 44->101. Experiment confounded; ILP theory not
// tested. R22 = minimal unconfounded test: R19's `#pragma unroll 1` was
// MY annotation forbidding cross-iteration hoisting — remove it (full
// unroll), let the compiler pick its own prefetch depth within budget
// (the regime where it performed well: R8 weights, R16 pk frags).
// (p&1) folds to a literal per pair. No other change.
// Validity gate: WRITE_SIZE ~16MB / FETCH ~29MB (no spill).
// Pre-committed read: clean + dur>=42us -> ILP hypothesis exhausted,
// k_gcn ~44us structural (TA-scatter bound).
// ---------------------------------------------------------------------------
__global__ __launch_bounds__(256) void k_gcn(
    const float* __restrict__ x,      // [B][T][218]
    float* __restrict__ hp)           // [B][64][T]
{
    const int b   = blockIdx.y;
    const int t0  = blockIdx.x * 64;
    const int tid = threadIdx.x;
    const int lane = tid & 63, wid = tid >> 6;
    const int l15 = lane & 15, lg = lane >> 4;
    const int t = t0 + wid * 16 + l15;
    const float* xrow = x + ((long)b * T_LEN + t) * 218;
    const int la8 = lane * 8;

    const float cP = 1.0f / 6.0f;
    const float cS = 0.23570226039551584f;   // 1/sqrt(18)
    const float c3 = 1.0f / 3.0f;
    const float cT = 0.4082482904638631f;    // 1/sqrt(6)
    const float cH = 0.5f;

    // ---- palm: h0 = x[0:18] . gcn_w  (K-pad lanes ch16..23, A=0 kills) ----
    f32x4 h0[4];
    {
        float vv[8];
        const int po = (lg < 2) ? lg * 8 : 16;
        *(float2*)(vv + 0) = *(const float2*)(xrow + po);
        *(float2*)(vv + 2) = *(const float2*)(xrow + po + 2);
        *(float2*)(vv + 4) = *(const float2*)(xrow + po + 4);
        *(float2*)(vv + 6) = *(const float2*)(xrow + po + 6);
        f16x8 bh, bl;
        #pragma unroll
        for (int j = 0; j < 8; ++j) {
            const f16 h = (f16)vv[j];
            bh[j] = h; bl[j] = (f16)(vv[j] - (float)h);
        }
        #pragma unroll
        for (int df = 0; df < 4; ++df) {
            const f16x8 ah = *(const f16x8*)(g_pk + (128 + df) * 1024 + la8);
            const f16x8 al = *(const f16x8*)(g_pk + (128 + df) * 1024 + 512 + la8);
            h0[df] = mfma3z(ah, al, bh, bl);
        }
    }

    // ---- bone-pair A-frags: register-resident, shared by all 10 pairs ----
    f16x8 A1h[4], A1l[4], A2h[4], A2l[4];
    #pragma unroll
    for (int df = 0; df < 4; ++df) {
        A1h[df] = *(const f16x8*)(g_pk + (124 + df) * 1024 + la8);
        A1l[df] = *(const f16x8*)(g_pk + (124 + df) * 1024 + 512 + la8);
        A2h[df] = *(const f16x8*)(g_pk + (132 + df) * 1024 + la8);
        A2l[df] = *(const f16x8*)(g_pk + (132 + df) * 1024 + 512 + la8);
    }

    f32x4 pool[4], star[4], s12[4], hprev[4];
    #pragma unroll
    for (int df = 0; df < 4; ++df) {
        pool[df] = (f32x4){0.f, 0.f, 0.f, 0.f};
        star[df] = (f32x4){0.f, 0.f, 0.f, 0.f};
    }

    // ---- bone pairs: p covers bones (2p, 2p+1); ch [18+20p, 18+20p+20) ----
    // FULL unroll: compiler free to hoist next pair's loads under this
    // pair's MFMAs at its own chosen depth (no forced 40-float batch).
    #pragma unroll
    for (int p = 0; p < 10; ++p) {
        const float* bp = xrow + 18 + 20 * p;
        float vv[8];
        if (lg < 2) {
            const float* q = bp + lg * 8;
            *(float2*)(vv + 0) = *(const float2*)(q);
            *(float2*)(vv + 2) = *(const float2*)(q + 2);
            *(float2*)(vv + 4) = *(const float2*)(q + 4);
            *(float2*)(vv + 6) = *(const float2*)(q + 6);
        } else if (lg == 2) {
            *(float2*)(vv + 0) = *(const float2*)(bp + 16);
            *(float2*)(vv + 2) = *(const float2*)(bp + 18);
            vv[4] = vv[5] = vv[6] = vv[7] = 0.f;
        } else {
            #pragma unroll
            for (int j = 0; j < 8; ++j) vv[j] = 0.f;
        }
        f16x8 bh, bl;
        #pragma unroll
        for (int j = 0; j < 8; ++j) {
            const f16 h = (f16)vv[j];
            bh[j] = h; bl[j] = (f16)(vv[j] - (float)h);
        }
        f32x4 hnA[4], hnB[4];
        #pragma unroll
        for (int df = 0; df < 4; ++df) {
            hnA[df] = mfma3z(A1h[df], A1l[df], bh, bl);  // bone 2p
            hnB[df] = mfma3z(A2h[df], A2l[df], bh, bl);  // bone 2p+1
        }

        if ((p & 1) == 0) {
            #pragma unroll
            for (int df = 0; df < 4; ++df)
                #pragma unroll
                for (int i = 0; i < 4; ++i) {
                    const float hA = hnA[df][i], hB = hnB[df][i];
                    star[df][i] += hA;
                    const float pa = fmaf(cS, h0[df][i], c3 * (hA + hB));
                    pool[df][i] += fmaxf(pa, 0.f);
                    s12[df][i] = hA + hB;
                    hprev[df][i] = hB;
                }
        } else {
            #pragma unroll
            for (int df = 0; df < 4; ++df)
                #pragma unroll
                for (int i = 0; i < 4; ++i) {
                    const float hA = hnA[df][i], hB = hnB[df][i];
                    const float pb = c3 * (s12[df][i] + hA);
                    pool[df][i] += fmaxf(pb, 0.f);
                    const float s2 = hprev[df][i] + hA;       // s12 after n=2
                    const float pc = fmaf(cT, hB, c3 * s2);
                    const float pe = fmaf(cT, hA, cH * hB);   // hprev(n3)=hA
                    pool[df][i] += fmaxf(pc, 0.f) + fmaxf(pe, 0.f);
                }
        }
    }

    float* hpb = hp + (long)b * 64 * T_LEN + t;
    #pragma unroll
    for (int df = 0; df < 4; ++df)
        #pragma unroll
        for (int i = 0; i < 4; ++i) {
            const float p0 = fmaf(cP, h0[df][i], cS * star[df][i]);
            hpb[(long)(df * 16 + lg * 4 + i) * T_LEN] =
                (pool[df][i] + fmaxf(p0, 0.f)) * (1.0f / 21.0f);
        }
}

// ---------------------------------------------------------------------------
// k_mstcn R20: PURE-F16 (1 MFMA per logical product). (unchanged — passed
// at absmax 1.5e-5, ~<43us each)
// ---------------------------------------------------------------------------
template <bool FINAL>
__global__ __launch_bounds__(512, 4) void k_mstcn(
    const float* __restrict__ in,   // [B][64][T]
    const float* __restrict__ bs, const float* __restrict__ bm,
    const float* __restrict__ bl, const float* __restrict__ bo,
    int pkoff,                      // layer * 61440 (f16 units)
    float* __restrict__ out,        // [B][64][T]  (FINAL=false)
    const float* __restrict__ bd,   // [32]        (FINAL=true)
    float* __restrict__ outp)       // [B][32]     (FINAL=true)
{
    __shared__ __align__(16) f16 lds[25600];   // 51200 B

    const int b   = blockIdx.y;
    const int t0  = blockIdx.x * 128;
    const int tid = threadIdx.x;
    const float* inb = in + (long)b * 64 * T_LEN;

    // ---- stage x [t0-32, t0+128) -> transposed f16 plane (linear) ----
    {
        const int c0 = (tid >> 4) * 2;      // channel pair 0..62
        const int tq = (tid & 15) * 10;     // 10 rows per thread
        float v0[10], v1[10];
        if (t0 != 0 || tq >= 40) {
            const float* r0 = inb + (long)c0 * T_LEN + (t0 - 32 + tq);
            const float* r1 = r0 + T_LEN;
            #pragma unroll
            for (int m = 0; m < 5; ++m) {
                *(float2*)(v0 + 2 * m) = *(const float2*)(r0 + 2 * m);
                *(float2*)(v1 + 2 * m) = *(const float2*)(r1 + 2 * m);
            }
        } else {
            #pragma unroll
            for (int i = 0; i < 10; ++i) {
                const int tg_ = tq + i - 32;
                v0[i] = (tg_ >= 0) ? inb[(long)c0 * T_LEN + tg_] : 0.f;
                v1[i] = (tg_ >= 0) ? inb[(long)(c0 + 1) * T_LEN + tg_] : 0.f;
            }
        }
        #pragma unroll
        for (int i = 0; i < 10; ++i) {
            const int row = tq + i;
            *(f16x2*)(&lds[row * 72 + c0]) = (f16x2){(f16)v0[i], (f16)v1[i]};
        }
    }
    __syncthreads();                         // b1

    const int lane = tid & 63, wid = tid >> 6;
    const int qh  = wid >> 2;                // channel half (K-split)
    const int tg  = wid & 3;                 // t-group (32 t each)
    const int l15 = lane & 15, lg = lane >> 4;
    const int tws0 = tg * 32, tws1 = tg * 32 + 16;
    const f16* pk = g_pk + pkoff;
    const int la8 = lane * 8;

#define MFMA1(ACC, AH, BH)                                                 \
        ACC = __builtin_amdgcn_mfma_f32_16x16x32_f16(AH, BH, ACC, 0, 0, 0)

#define LOADA(AH, FR) AH = *(const f16x8*)(pk + (FR) * 1024 + la8)

#define BRD(BH, ROW) BH = *(const f16x8*)(&lds[(ROW) * 72 + qh * 32 + lg * 8])

    // ---- GEMM1: branches, channel-half qh, 2 t-subtiles. C[j][t] ----
    f32x4 aS0 = {0.f,0.f,0.f,0.f}, aS1 = {0.f,0.f,0.f,0.f};
    f32x4 aM0 = {0.f,0.f,0.f,0.f}, aM1 = {0.f,0.f,0.f,0.f};
    f32x4 aL00 = {0.f,0.f,0.f,0.f}, aL01 = {0.f,0.f,0.f,0.f};
    f32x4 aL10 = {0.f,0.f,0.f,0.f}, aL11 = {0.f,0.f,0.f,0.f};

    #pragma unroll
    for (int kp = 0; kp < 3; ++kp) {
        f16x8 ah, bh;
        LOADA(ah, 2 * kp + qh);
        BRD(bh, 30 + tws0 + l15 + kp); MFMA1(aS0, ah, bh);
        BRD(bh, 30 + tws1 + l15 + kp); MFMA1(aS1, ah, bh);
    }
    #pragma unroll
    for (int kp = 0; kp < 5; ++kp) {
        f16x8 ah, bh;
        LOADA(ah, 6 + 2 * kp + qh);
        BRD(bh, 24 + tws0 + l15 + 2 * kp); MFMA1(aM0, ah, bh);
        BRD(bh, 24 + tws1 + l15 + 2 * kp); MFMA1(aM1, ah, bh);
    }
    #pragma unroll
    for (int kp = 0; kp < 9; ++kp) {
        f16x8 a0h, a1h, bh;
        LOADA(a0h, 16 + 4 * kp + 2 * qh);
        LOADA(a1h, 16 + 4 * kp + 2 * qh + 1);
        BRD(bh, tws0 + l15 + 4 * kp);
        MFMA1(aL00, a0h, bh); MFMA1(aL10, a1h, bh);
        BRD(bh, tws1 + l15 + 4 * kp);
        MFMA1(aL01, a0h, bh); MFMA1(aL11, a1h, bh);
    }

    __syncthreads();                         // b2: X dead, RED live
    {
        float* red = (float*)lds;
        const int ro = (tg * 64 + lane) * 4; // 16B lane stride: conflict-free
        if (qh == 0) {
            *(f32x4*)(red + 0 * 1024 + ro) = aS0;
            *(f32x4*)(red + 1 * 1024 + ro) = aM0;
            *(f32x4*)(red + 2 * 1024 + ro) = aL00;
            *(f32x4*)(red + 3 * 1024 + ro) = aL10;
            *(f32x4*)(red + 4 * 1024 + ro) = aS1;
            *(f32x4*)(red + 5 * 1024 + ro) = aM1;
            *(f32x4*)(red + 6 * 1024 + ro) = aL01;
            *(f32x4*)(red + 7 * 1024 + ro) = aL11;
        }
        __syncthreads();                     // b3: last barrier (qh0 exits)
        if (qh == 0) return;
        aS0  += *(const f32x4*)(red + 0 * 1024 + ro);
        aM0  += *(const f32x4*)(red + 1 * 1024 + ro);
        aL00 += *(const f32x4*)(red + 2 * 1024 + ro);
        aL10 += *(const f32x4*)(red + 3 * 1024 + ro);
        aS1  += *(const f32x4*)(red + 4 * 1024 + ro);
        aM1  += *(const f32x4*)(red + 5 * 1024 + ro);
        aL01 += *(const f32x4*)(red + 6 * 1024 + ro);
        aL11 += *(const f32x4*)(red + 7 * 1024 + ro);
    }

    // ---- bias (+relu) + f16 stage into HH plane [t][j] (linear) ----
#define STAGEH(ACC, BPTR, JB, RELU, RB) do {                               \
        const float4 bv_ = *(const float4*)(BPTR);                         \
        float x0_ = ACC[0] + bv_.x, x1_ = ACC[1] + bv_.y,                  \
              x2_ = ACC[2] + bv_.z, x3_ = ACC[3] + bv_.w;                  \
        if (RELU) { x0_ = fmaxf(x0_, 0.f); x1_ = fmaxf(x1_, 0.f);          \
                    x2_ = fmaxf(x2_, 0.f); x3_ = fmaxf(x3_, 0.f); }        \
        const int ro_ = ((RB) + l15) * 72 + (JB) + lg * 4;                 \
        *(f16x2*)(&lds[16384 + ro_])     = (f16x2){(f16)x0_, (f16)x1_};    \
        *(f16x2*)(&lds[16384 + ro_ + 2]) = (f16x2){(f16)x2_, (f16)x3_};    \
    } while (0)

    STAGEH(aS0,  bs + lg * 4,       0,  true, tws0);
    STAGEH(aM0,  bm + lg * 4,       16, true, tws0);
    STAGEH(aL00, bl + lg * 4,       32, true, tws0);
    STAGEH(aL10, bl + 16 + lg * 4,  48, true, tws0);
    STAGEH(aS1,  bs + lg * 4,       0,  true, tws1);
    STAGEH(aM1,  bm + lg * 4,       16, true, tws1);
    STAGEH(aL01, bl + lg * 4,       32, true, tws1);
    STAGEH(aL11, bl + 16 + lg * 4,  48, true, tws1);
    // no barrier: wave reads only its own 32 H rows below

#define HRD(BH, RB, KH)                                                    \
        BH = *(const f16x8*)(&lds[16384 + ((RB) + l15) * 72 + (KH) * 32 + lg * 8])

    // ---- GEMM2: conv_out 64->64.  C[d][t], 2 subtiles ----
    f32x4 oA0 = {0.f,0.f,0.f,0.f}, oA1 = {0.f,0.f,0.f,0.f};
    f32x4 oA2 = {0.f,0.f,0.f,0.f}, oA3 = {0.f,0.f,0.f,0.f};
    f32x4 oB0 = {0.f,0.f,0.f,0.f}, oB1 = {0.f,0.f,0.f,0.f};
    f32x4 oB2 = {0.f,0.f,0.f,0.f}, oB3 = {0.f,0.f,0.f,0.f};
    #pragma unroll
    for (int kh = 0; kh < 2; ++kh) {
        f16x8 b0h, b1h, ah;
        HRD(b0h, tws0, kh);
        HRD(b1h, tws1, kh);
        LOADA(ah, 52 + 0 + kh); MFMA1(oA0, ah, b0h); MFMA1(oB0, ah, b1h);
        LOADA(ah, 52 + 2 + kh); MFMA1(oA1, ah, b0h); MFMA1(oB1, ah, b1h);
        LOADA(ah, 52 + 4 + kh); MFMA1(oA2, ah, b0h); MFMA1(oB2, ah, b1h);
        LOADA(ah, 52 + 6 + kh); MFMA1(oA3, ah, b0h); MFMA1(oB3, ah, b1h);
    }

    if (!FINAL) {
        const float4 b0v = *(const float4*)(bo + lg * 4);
        const float4 b1v = *(const float4*)(bo + 16 + lg * 4);
        const float4 b2v = *(const float4*)(bo + 32 + lg * 4);
        const float4 b3v = *(const float4*)(bo + 48 + lg * 4);
#define STO4(ACC, BV, MS, OB) do {                                         \
        (OB)[((MS) * 16 + lg * 4 + 0) * (long)T_LEN] = ACC[0] + BV.x;      \
        (OB)[((MS) * 16 + lg * 4 + 1) * (long)T_LEN] = ACC[1] + BV.y;      \
        (OB)[((MS) * 16 + lg * 4 + 2) * (long)T_LEN] = ACC[2] + BV.z;      \
        (OB)[((MS) * 16 + lg * 4 + 3) * (long)T_LEN] = ACC[3] + BV.w;      \
    } while (0)
        float* obA = out + (long)b * 64 * T_LEN + t0 + tws0 + l15;
        float* obB = out + (long)b * 64 * T_LEN + t0 + tws1 + l15;
        STO4(oA0, b0v, 0, obA); STO4(oB0, b0v, 0, obB);
        STO4(oA1, b1v, 1, obA); STO4(oB1, b1v, 1, obB);
        STO4(oA2, b2v, 2, obA); STO4(oB2, b2v, 2, obB);
        STO4(oA3, b3v, 3, obA); STO4(oB3, b3v, 3, obB);
#undef STO4
    } else {
        // ---- stage t2 (conv_out + bo, no relu); wave-local rows ----
        STAGEH(oA0, bo + lg * 4,       0,  false, tws0);
        STAGEH(oA1, bo + 16 + lg * 4,  16, false, tws0);
        STAGEH(oA2, bo + 32 + lg * 4,  32, false, tws0);
        STAGEH(oA3, bo + 48 + lg * 4,  48, false, tws0);
        STAGEH(oB0, bo + lg * 4,       0,  false, tws1);
        STAGEH(oB1, bo + 16 + lg * 4,  16, false, tws1);
        STAGEH(oB2, bo + 32 + lg * 4,  32, false, tws1);
        STAGEH(oB3, bo + 48 + lg * 4,  48, false, tws1);

        // ---- GEMM3: dense 64->32.  C[e][t], 2 subtiles ----
        f32x4 eA0 = {0.f,0.f,0.f,0.f}, eA1 = {0.f,0.f,0.f,0.f};
        f32x4 eB0 = {0.f,0.f,0.f,0.f}, eB1 = {0.f,0.f,0.f,0.f};
        #pragma unroll
        for (int kh = 0; kh < 2; ++kh) {
            f16x8 b0h, b1h, ah;
            HRD(b0h, tws0, kh);
            HRD(b1h, tws1, kh);
            ah = *(const f16x8*)(g_pk + (120 + 0 + kh) * 1024 + la8);
            MFMA1(eA0, ah, b0h); MFMA1(eB0, ah, b1h);
            ah = *(const f16x8*)(g_pk + (120 + 2 + kh) * 1024 + la8);
            MFMA1(eA1, ah, b0h); MFMA1(eB1, ah, b1h);
        }
        const float4 bd0 = *(const float4*)(bd + lg * 4);
        const float4 bd1 = *(const float4*)(bd + 16 + lg * 4);
        const float cI = 1.0f / (float)T_LEN;
        float u0 = (tanhf(eA0[0] + bd0.x) + tanhf(eB0[0] + bd0.x)) * cI;
        float u1 = (tanhf(eA0[1] + bd0.y) + tanhf(eB0[1] + bd0.y)) * cI;
        float u2 = (tanhf(eA0[2] + bd0.z) + tanhf(eB0[2] + bd0.z)) * cI;
        float u3 = (tanhf(eA0[3] + bd0.w) + tanhf(eB0[3] + bd0.w)) * cI;
        float u4 = (tanhf(eA1[0] + bd1.x) + tanhf(eB1[0] + bd1.x)) * cI;
        float u5 = (tanhf(eA1[1] + bd1.y) + tanhf(eB1[1] + bd1.y)) * cI;
        float u6 = (tanhf(eA1[2] + bd1.z) + tanhf(eB1[2] + bd1.z)) * cI;
        float u7 = (tanhf(eA1[3] + bd1.w) + tanhf(eB1[3] + bd1.w)) * cI;
#define RED(U) do { U += __shfl_xor(U, 1); U += __shfl_xor(U, 2);          \
                    U += __shfl_xor(U, 4); U += __shfl_xor(U, 8); } while (0)
        RED(u0); RED(u1); RED(u2); RED(u3);
        RED(u4); RED(u5); RED(u6); RED(u7);
#undef RED
        if (l15 == 0) {
            float* op = outp + b * 32;
            atomicAdd(op + lg * 4 + 0, u0);
            atomicAdd(op + lg * 4 + 1, u1);
            atomicAdd(op + lg * 4 + 2, u2);
            atomicAdd(op + lg * 4 + 3, u3);
            atomicAdd(op + 16 + lg * 4 + 0, u4);
            atomicAdd(op + 16 + lg * 4 + 1, u5);
            atomicAdd(op + 16 + lg * 4 + 2, u6);
            atomicAdd(op + 16 + lg * 4 + 3, u7);
        }
    }
#undef HRD
#undef STAGEH
#undef BRD
#undef LOADA
#undef MFMA1
}

extern "C" void kernel_launch(void* const* d_in, const int* in_sizes, int n_in,
                              void* d_out, int out_size, void* d_ws, size_t ws_size,
                              hipStream_t stream) {
    const float* x     = (const float*)d_in[0];
    const float* gcn_w = (const float*)d_in[1];
    const float* wd    = (const float*)d_in[2];
    const float* bd    = (const float*)d_in[3];
    const float* t1_ws = (const float*)d_in[4];
    const float* t1_bs = (const float*)d_in[5];
    const float* t1_wm = (const float*)d_in[6];
    const float* t1_bm = (const float*)d_in[7];
    const float* t1_wl = (const float*)d_in[8];
    const float* t1_bl = (const float*)d_in[9];
    const float* t1_wo = (const float*)d_in[10];
    const float* t1_bo = (const float*)d_in[11];
    const float* t2_ws = (const float*)d_in[12];
    const float* t2_bs = (const float*)d_in[13];
    const float* t2_wm = (const float*)d_in[14];
    const float* t2_bm = (const float*)d_in[15];
    const float* t2_wl = (const float*)d_in[16];
    const float* t2_bl = (const float*)d_in[17];
    const float* t2_wo = (const float*)d_in[18];
    const float* t2_bo = (const float*)d_in[19];

    float* b0 = (float*)d_ws;                          // [16][64][4096]
    float* b1 = b0 + (size_t)BATCH * 64 * T_LEN;       // [16][64][4096]

    hipMemsetAsync(d_out, 0, (size_t)out_size * sizeof(float), stream);

    k_pack<<<dim3(136), 256, 0, stream>>>(
        t1_ws, t1_wm, t1_wl, t1_wo, t2_ws, t2_wm, t2_wl, t2_wo, wd, gcn_w);

    k_gcn<<<dim3(T_LEN / 64, BATCH), 256, 0, stream>>>(x, b0);

    k_mstcn<false><<<dim3(T_LEN / 128, BATCH), 512, 0, stream>>>(
        b0, t1_bs, t1_bm, t1_bl, t1_bo, 0,
        b1, nullptr, nullptr);

    k_mstcn<true><<<dim3(T_LEN / 128, BATCH), 512, 0, stream>>>(
        b1, t2_bs, t2_bm, t2_bl, t2_bo, 61440,
        nullptr, bd, (float*)d_out);
}

// Round 16
// 186.837 us; speedup vs baseline: 1.3128x; 1.0794x over previous
//
#include <hip/hip_runtime.h>
#include <hip/hip_bf16.h>
#include <math.h>

#define T_LEN 4096
#define BATCH 16

typedef _Float16 f16;
typedef _Float16 f16x2 __attribute__((ext_vector_type(2)));
typedef _Float16 f16x8 __attribute__((ext_vector_type(8)));
typedef float f32x4 __attribute__((ext_vector_type(4)));

// Packed MFMA A-fragments, hi/lo split-f16. 136 logical frags:
// per layer (60): S[k(3)][q(2)]=0..5, M[k(5)][q(2)]=6..15,
// L[k(9)][q(2)][ms(2)]=16..51, O[ms(4)][kh(2)]=52..59; layer stride 60.
// D (dense 64->32): 120..123 = [ms(2)][kh(2)].
// GCN: 124..127 = bone proj A1[df]; 128..131 = palm proj A[df];
//      132..135 = bone proj A2[df].
// Frag f: hi at f*1024 + lane*8, lo at f*1024 + 512 + lane*8 (f16 units).
// k_mstcn uses HI halves only (pure-f16, R20); k_gcn uses hi+lo (3-MFMA).
__device__ __align__(16) f16 g_pk[136 * 1024];

// ---------------------------------------------------------------------------
// k_pack: one-time weight repack -> MFMA fragments (hi/lo f16). (unchanged)
// ---------------------------------------------------------------------------
__global__ void k_pack(
    const float* __restrict__ ws1, const float* __restrict__ wm1,
    const float* __restrict__ wl1, const float* __restrict__ wo1,
    const float* __restrict__ ws2, const float* __restrict__ wm2,
    const float* __restrict__ wl2, const float* __restrict__ wo2,
    const float* __restrict__ wd,  const float* __restrict__ gcn_w)
{
    const int g = blockIdx.x;          // 0..135 logical frag
    const int tid = threadIdx.x;
    #pragma unroll
    for (int u = 0; u < 2; ++u) {
        const int e = tid * 2 + u;     // 0..511
        const int lane = e >> 3, j = e & 7;
        const int m = lane & 15, k = (lane >> 4) * 8 + j;
        float w;
        if (g < 120) {
            const int layer = g / 60, r0 = g % 60;
            const float* pws = layer ? ws2 : ws1;
            const float* pwm = layer ? wm2 : wm1;
            const float* pwl = layer ? wl2 : wl1;
            const float* pwo = layer ? wo2 : wo1;
            if (r0 < 6) {
                const int kp = r0 >> 1, q = r0 & 1;
                w = pws[(kp * 64 + q * 32 + k) * 16 + m];        // ws[k][c][j]
            } else if (r0 < 16) {
                const int r = r0 - 6, kp = r >> 1, q = r & 1;
                w = pwm[(kp * 64 + q * 32 + k) * 16 + m];
            } else if (r0 < 52) {
                const int r = r0 - 16, kp = r >> 2, q = (r >> 1) & 1, ms = r & 1;
                w = pwl[(kp * 64 + q * 32 + k) * 32 + ms * 16 + m];
            } else {
                const int r = r0 - 52, ms = r >> 1, kh = r & 1;
                w = pwo[(kh * 32 + k) * 64 + ms * 16 + m];       // wo[j][d] -> A[d][j]
            }
        } else if (g < 124) {
            const int r = g - 120, ms = r >> 1, kh = r & 1;
            w = wd[(kh * 32 + k) * 32 + ms * 16 + m];            // wd[d][e] -> A[e][d]
        } else if (g < 132) {
            const int r = g - 124, df = r & 3;
            const int lim = (r >> 2) ? 18 : 10;                  // palm : bone A1
            w = (k < lim) ? gcn_w[k * 64 + df * 16 + m] : 0.f;
        } else {
            const int df = (g - 132) & 3;                        // bone A2
            w = (k >= 10 && k < 20) ? gcn_w[(k - 10) * 64 + df * 16 + m] : 0.f;
        }
        const f16 hi = (f16)w;
        const f16 lo = (f16)(w - (float)hi);
        g_pk[g * 1024 + e] = hi;
        g_pk[g * 1024 + 512 + e] = lo;
    }
}

__device__ inline f32x4 mfma3z(f16x8 ah, f16x8 al, f16x8 bh, f16x8 bl) {
    f32x4 a = {0.f, 0.f, 0.f, 0.f};
    a = __builtin_amdgcn_mfma_f32_16x16x32_f16(ah, bh, a, 0, 0, 0);
    a = __builtin_amdgcn_mfma_f32_16x16x32_f16(ah, bl, a, 0, 0, 0);
    a = __builtin_amdgcn_mfma_f32_16x16x32_f16(al, bh, a, 0, 0, 0);
    return a;
}

// ---------------------------------------------------------------------------
// k_gcn R23: R19 body with `#pragma unroll 2` on the pair loop.
// Unroll-depth axis so far: depth-1 serial = 44-50us (R19/R20); depth-5
// hand-batch = catastrophic spill (R21, 195MB scratch); depth-10 full
// unroll = 256 VGPR + mild spill + 9% occ = 62us (R22). Depth 2 is the
// only unexplored point and the only one whose live-range cost (~+12-16
// VGPR: one vv[8] + one bh/bl pair) trivially fits R19's 128-VGPR slack.
// One-pair lookahead lets the scheduler overlap pair p+1's 4 loads with
// pair p's 24 MFMAs without forcing a big batch window.
// No-spill gate: WRITE_SIZE ~16MB. Null/regress -> k_gcn plateau is
// confirmed across the whole axis; revert to R20 config as final.
// ---------------------------------------------------------------------------
__global__ __launch_bounds__(256) void k_gcn(
    const float* __restrict__ x,      // [B][T][218]
    float* __restrict__ hp)           // [B][64][T]
{
    const int b   = blockIdx.y;
    const int t0  = blockIdx.x * 64;
    const int tid = threadIdx.x;
    const int lane = tid & 63, wid = tid >> 6;
    const int l15 = lane & 15, lg = lane >> 4;
    const int t = t0 + wid * 16 + l15;
    const float* xrow = x + ((long)b * T_LEN + t) * 218;
    const int la8 = lane * 8;

    const float cP = 1.0f / 6.0f;
    const float cS = 0.23570226039551584f;   // 1/sqrt(18)
    const float c3 = 1.0f / 3.0f;
    const float cT = 0.4082482904638631f;    // 1/sqrt(6)
    const float cH = 0.5f;

    // ---- palm: h0 = x[0:18] . gcn_w  (K-pad lanes ch16..23, A=0 kills) ----
    f32x4 h0[4];
    {
        float vv[8];
        const int po = (lg < 2) ? lg * 8 : 16;
        *(float2*)(vv + 0) = *(const float2*)(xrow + po);
        *(float2*)(vv + 2) = *(const float2*)(xrow + po + 2);
        *(float2*)(vv + 4) = *(const float2*)(xrow + po + 4);
        *(float2*)(vv + 6) = *(const float2*)(xrow + po + 6);
        f16x8 bh, bl;
        #pragma unroll
        for (int j = 0; j < 8; ++j) {
            const f16 h = (f16)vv[j];
            bh[j] = h; bl[j] = (f16)(vv[j] - (float)h);
        }
        #pragma unroll
        for (int df = 0; df < 4; ++df) {
            const f16x8 ah = *(const f16x8*)(g_pk + (128 + df) * 1024 + la8);
            const f16x8 al = *(const f16x8*)(g_pk + (128 + df) * 1024 + 512 + la8);
            h0[df] = mfma3z(ah, al, bh, bl);
        }
    }

    // ---- bone-pair A-frags: register-resident, shared by all 10 pairs ----
    f16x8 A1h[4], A1l[4], A2h[4], A2l[4];
    #pragma unroll
    for (int df = 0; df < 4; ++df) {
        A1h[df] = *(const f16x8*)(g_pk + (124 + df) * 1024 + la8);
        A1l[df] = *(const f16x8*)(g_pk + (124 + df) * 1024 + 512 + la8);
        A2h[df] = *(const f16x8*)(g_pk + (132 + df) * 1024 + la8);
        A2l[df] = *(const f16x8*)(g_pk + (132 + df) * 1024 + 512 + la8);
    }

    f32x4 pool[4], star[4], s12[4], hprev[4];
    #pragma unroll
    for (int df = 0; df < 4; ++df) {
        pool[df] = (f32x4){0.f, 0.f, 0.f, 0.f};
        star[df] = (f32x4){0.f, 0.f, 0.f, 0.f};
    }

    // ---- bone pairs: p covers bones (2p, 2p+1); ch [18+20p, 18+20p+20) ----
    // unroll 2: one-pair load lookahead (+~12-16 VGPR), no big batch.
    #pragma unroll 2
    for (int p = 0; p < 10; ++p) {
        const float* bp = xrow + 18 + 20 * p;
        float vv[8];
        if (lg < 2) {
            const float* q = bp + lg * 8;
            *(float2*)(vv + 0) = *(const float2*)(q);
            *(float2*)(vv + 2) = *(const float2*)(q + 2);
            *(float2*)(vv + 4) = *(const float2*)(q + 4);
            *(float2*)(vv + 6) = *(const float2*)(q + 6);
        } else if (lg == 2) {
            *(float2*)(vv + 0) = *(const float2*)(bp + 16);
            *(float2*)(vv + 2) = *(const float2*)(bp + 18);
            vv[4] = vv[5] = vv[6] = vv[7] = 0.f;
        } else {
            #pragma unroll
            for (int j = 0; j < 8; ++j) vv[j] = 0.f;
        }
        f16x8 bh, bl;
        #pragma unroll
        for (int j = 0; j < 8; ++j) {
            const f16 h = (f16)vv[j];
            bh[j] = h; bl[j] = (f16)(vv[j] - (float)h);
        }
        f32x4 hnA[4], hnB[4];
        #pragma unroll
        for (int df = 0; df < 4; ++df) {
            hnA[df] = mfma3z(A1h[df], A1l[df], bh, bl);  // bone 2p
            hnB[df] = mfma3z(A2h[df], A2l[df], bh, bl);  // bone 2p+1
        }

        if ((p & 1) == 0) {
            #pragma unroll
            for (int df = 0; df < 4; ++df)
                #pragma unroll
                for (int i = 0; i < 4; ++i) {
                    const float hA = hnA[df][i], hB = hnB[df][i];
                    star[df][i] += hA;
                    const float pa = fmaf(cS, h0[df][i], c3 * (hA + hB));
                    pool[df][i] += fmaxf(pa, 0.f);
                    s12[df][i] = hA + hB;
                    hprev[df][i] = hB;
                }
        } else {
            #pragma unroll
            for (int df = 0; df < 4; ++df)
                #pragma unroll
                for (int i = 0; i < 4; ++i) {
                    const float hA = hnA[df][i], hB = hnB[df][i];
                    const float pb = c3 * (s12[df][i] + hA);
                    pool[df][i] += fmaxf(pb, 0.f);
                    const float s2 = hprev[df][i] + hA;       // s12 after n=2
                    const float pc = fmaf(cT, hB, c3 * s2);
                    const float pe = fmaf(cT, hA, cH * hB);   // hprev(n3)=hA
                    pool[df][i] += fmaxf(pc, 0.f) + fmaxf(pe, 0.f);
                }
        }
    }

    float* hpb = hp + (long)b * 64 * T_LEN + t;
    #pragma unroll
    for (int df = 0; df < 4; ++df)
        #pragma unroll
        for (int i = 0; i < 4; ++i) {
            const float p0 = fmaf(cP, h0[df][i], cS * star[df][i]);
            hpb[(long)(df * 16 + lg * 4 + i) * T_LEN] =
                (pool[df][i] + fmaxf(p0, 0.f)) * (1.0f / 21.0f);
        }
}

// ---------------------------------------------------------------------------
// k_mstcn R20: PURE-F16 (1 MFMA per logical product). (unchanged — passed
// at absmax 1.5e-5, ~<43us each)
// ---------------------------------------------------------------------------
template <bool FINAL>
__global__ __launch_bounds__(512, 4) void k_mstcn(
    const float* __restrict__ in,   // [B][64][T]
    const float* __restrict__ bs, const float* __restrict__ bm,
    const float* __restrict__ bl, const float* __restrict__ bo,
    int pkoff,                      // layer * 61440 (f16 units)
    float* __restrict__ out,        // [B][64][T]  (FINAL=false)
    const float* __restrict__ bd,   // [32]        (FINAL=true)
    float* __restrict__ outp)       // [B][32]     (FINAL=true)
{
    __shared__ __align__(16) f16 lds[25600];   // 51200 B

    const int b   = blockIdx.y;
    const int t0  = blockIdx.x * 128;
    const int tid = threadIdx.x;
    const float* inb = in + (long)b * 64 * T_LEN;

    // ---- stage x [t0-32, t0+128) -> transposed f16 plane (linear) ----
    {
        const int c0 = (tid >> 4) * 2;      // channel pair 0..62
        const int tq = (tid & 15) * 10;     // 10 rows per thread
        float v0[10], v1[10];
        if (t0 != 0 || tq >= 40) {
            const float* r0 = inb + (long)c0 * T_LEN + (t0 - 32 + tq);
            const float* r1 = r0 + T_LEN;
            #pragma unroll
            for (int m = 0; m < 5; ++m) {
                *(float2*)(v0 + 2 * m) = *(const float2*)(r0 + 2 * m);
                *(float2*)(v1 + 2 * m) = *(const float2*)(r1 + 2 * m);
            }
        } else {
            #pragma unroll
            for (int i = 0; i < 10; ++i) {
                const int tg_ = tq + i - 32;
                v0[i] = (tg_ >= 0) ? inb[(long)c0 * T_LEN + tg_] : 0.f;
                v1[i] = (tg_ >= 0) ? inb[(long)(c0 + 1) * T_LEN + tg_] : 0.f;
            }
        }
        #pragma unroll
        for (int i = 0; i < 10; ++i) {
            const int row = tq + i;
            *(f16x2*)(&lds[row * 72 + c0]) = (f16x2){(f16)v0[i], (f16)v1[i]};
        }
    }
    __syncthreads();                         // b1

    const int lane = tid & 63, wid = tid >> 6;
    const int qh  = wid >> 2;                // channel half (K-split)
    const int tg  = wid & 3;                 // t-group (32 t each)
    const int l15 = lane & 15, lg = lane >> 4;
    const int tws0 = tg * 32, tws1 = tg * 32 + 16;
    const f16* pk = g_pk + pkoff;
    const int la8 = lane * 8;

#define MFMA1(ACC, AH, BH)                                                 \
        ACC = __builtin_amdgcn_mfma_f32_16x16x32_f16(AH, BH, ACC, 0, 0, 0)

#define LOADA(AH, FR) AH = *(const f16x8*)(pk + (FR) * 1024 + la8)

#define BRD(BH, ROW) BH = *(const f16x8*)(&lds[(ROW) * 72 + qh * 32 + lg * 8])

    // ---- GEMM1: branches, channel-half qh, 2 t-subtiles. C[j][t] ----
    f32x4 aS0 = {0.f,0.f,0.f,0.f}, aS1 = {0.f,0.f,0.f,0.f};
    f32x4 aM0 = {0.f,0.f,0.f,0.f}, aM1 = {0.f,0.f,0.f,0.f};
    f32x4 aL00 = {0.f,0.f,0.f,0.f}, aL01 = {0.f,0.f,0.f,0.f};
    f32x4 aL10 = {0.f,0.f,0.f,0.f}, aL11 = {0.f,0.f,0.f,0.f};

    #pragma unroll
    for (int kp = 0; kp < 3; ++kp) {
        f16x8 ah, bh;
        LOADA(ah, 2 * kp + qh);
        BRD(bh, 30 + tws0 + l15 + kp); MFMA1(aS0, ah, bh);
        BRD(bh, 30 + tws1 + l15 + kp); MFMA1(aS1, ah, bh);
    }
    #pragma unroll
    for (int kp = 0; kp < 5; ++kp) {
        f16x8 ah, bh;
        LOADA(ah, 6 + 2 * kp + qh);
        BRD(bh, 24 + tws0 + l15 + 2 * kp); MFMA1(aM0, ah, bh);
        BRD(bh, 24 + tws1 + l15 + 2 * kp); MFMA1(aM1, ah, bh);
    }
    #pragma unroll
    for (int kp = 0; kp < 9; ++kp) {
        f16x8 a0h, a1h, bh;
        LOADA(a0h, 16 + 4 * kp + 2 * qh);
        LOADA(a1h, 16 + 4 * kp + 2 * qh + 1);
        BRD(bh, tws0 + l15 + 4 * kp);
        MFMA1(aL00, a0h, bh); MFMA1(aL10, a1h, bh);
        BRD(bh, tws1 + l15 + 4 * kp);
        MFMA1(aL01, a0h, bh); MFMA1(aL11, a1h, bh);
    }

    __syncthreads();                         // b2: X dead, RED live
    {
        float* red = (float*)lds;
        const int ro = (tg * 64 + lane) * 4; // 16B lane stride: conflict-free
        if (qh == 0) {
            *(f32x4*)(red + 0 * 1024 + ro) = aS0;
            *(f32x4*)(red + 1 * 1024 + ro) = aM0;
            *(f32x4*)(red + 2 * 1024 + ro) = aL00;
            *(f32x4*)(red + 3 * 1024 + ro) = aL10;
            *(f32x4*)(red + 4 * 1024 + ro) = aS1;
            *(f32x4*)(red + 5 * 1024 + ro) = aM1;
            *(f32x4*)(red + 6 * 1024 + ro) = aL01;
            *(f32x4*)(red + 7 * 1024 + ro) = aL11;
        }
        __syncthreads();                     // b3: last barrier (qh0 exits)
        if (qh == 0) return;
        aS0  += *(const f32x4*)(red + 0 * 1024 + ro);
        aM0  += *(const f32x4*)(red + 1 * 1024 + ro);
        aL00 += *(const f32x4*)(red + 2 * 1024 + ro);
        aL10 += *(const f32x4*)(red + 3 * 1024 + ro);
        aS1  += *(const f32x4*)(red + 4 * 1024 + ro);
        aM1  += *(const f32x4*)(red + 5 * 1024 + ro);
        aL01 += *(const f32x4*)(red + 6 * 1024 + ro);
        aL11 += *(const f32x4*)(red + 7 * 1024 + ro);
    }

    // ---- bias (+relu) + f16 stage into HH plane [t][j] (linear) ----
#define STAGEH(ACC, BPTR, JB, RELU, RB) do {                               \
        const float4 bv_ = *(const float4*)(BPTR);                         \
        float x0_ = ACC[0] + bv_.x, x1_ = ACC[1] + bv_.y,                  \
              x2_ = ACC[2] + bv_.z, x3_ = ACC[3] + bv_.w;                  \
        if (RELU) { x0_ = fmaxf(x0_, 0.f); x1_ = fmaxf(x1_, 0.f);          \
                    x2_ = fmaxf(x2_, 0.f); x3_ = fmaxf(x3_, 0.f); }        \
        const int ro_ = ((RB) + l15) * 72 + (JB) + lg * 4;                 \
        *(f16x2*)(&lds[16384 + ro_])     = (f16x2){(f16)x0_, (f16)x1_};    \
        *(f16x2*)(&lds[16384 + ro_ + 2]) = (f16x2){(f16)x2_, (f16)x3_};    \
    } while (0)

    STAGEH(aS0,  bs + lg * 4,       0,  true, tws0);
    STAGEH(aM0,  bm + lg * 4,       16, true, tws0);
    STAGEH(aL00, bl + lg * 4,       32, true, tws0);
    STAGEH(aL10, bl + 16 + lg * 4,  48, true, tws0);
    STAGEH(aS1,  bs + lg * 4,       0,  true, tws1);
    STAGEH(aM1,  bm + lg * 4,       16, true, tws1);
    STAGEH(aL01, bl + lg * 4,       32, true, tws1);
    STAGEH(aL11, bl + 16 + lg * 4,  48, true, tws1);
    // no barrier: wave reads only its own 32 H rows below

#define HRD(BH, RB, KH)                                                    \
        BH = *(const f16x8*)(&lds[16384 + ((RB) + l15) * 72 + (KH) * 32 + lg * 8])

    // ---- GEMM2: conv_out 64->64.  C[d][t], 2 subtiles ----
    f32x4 oA0 = {0.f,0.f,0.f,0.f}, oA1 = {0.f,0.f,0.f,0.f};
    f32x4 oA2 = {0.f,0.f,0.f,0.f}, oA3 = {0.f,0.f,0.f,0.f};
    f32x4 oB0 = {0.f,0.f,0.f,0.f}, oB1 = {0.f,0.f,0.f,0.f};
    f32x4 oB2 = {0.f,0.f,0.f,0.f}, oB3 = {0.f,0.f,0.f,0.f};
    #pragma unroll
    for (int kh = 0; kh < 2; ++kh) {
        f16x8 b0h, b1h, ah;
        HRD(b0h, tws0, kh);
        HRD(b1h, tws1, kh);
        LOADA(ah, 52 + 0 + kh); MFMA1(oA0, ah, b0h); MFMA1(oB0, ah, b1h);
        LOADA(ah, 52 + 2 + kh); MFMA1(oA1, ah, b0h); MFMA1(oB1, ah, b1h);
        LOADA(ah, 52 + 4 + kh); MFMA1(oA2, ah, b0h); MFMA1(oB2, ah, b1h);
        LOADA(ah, 52 + 6 + kh); MFMA1(oA3, ah, b0h); MFMA1(oB3, ah, b1h);
    }

    if (!FINAL) {
        const float4 b0v = *(const float4*)(bo + lg * 4);
        const float4 b1v = *(const float4*)(bo + 16 + lg * 4);
        const float4 b2v = *(const float4*)(bo + 32 + lg * 4);
        const float4 b3v = *(const float4*)(bo + 48 + lg * 4);
#define STO4(ACC, BV, MS, OB) do {                                         \
        (OB)[((MS) * 16 + lg * 4 + 0) * (long)T_LEN] = ACC[0] + BV.x;      \
        (OB)[((MS) * 16 + lg * 4 + 1) * (long)T_LEN] = ACC[1] + BV.y;      \
        (OB)[((MS) * 16 + lg * 4 + 2) * (long)T_LEN] = ACC[2] + BV.z;      \
        (OB)[((MS) * 16 + lg * 4 + 3) * (long)T_LEN] = ACC[3] + BV.w;      \
    } while (0)
        float* obA = out + (long)b * 64 * T_LEN + t0 + tws0 + l15;
        float* obB = out + (long)b * 64 * T_LEN + t0 + tws1 + l15;
        STO4(oA0, b0v, 0, obA); STO4(oB0, b0v, 0, obB);
        STO4(oA1, b1v, 1, obA); STO4(oB1, b1v, 1, obB);
        STO4(oA2, b2v, 2, obA); STO4(oB2, b2v, 2, obB);
        STO4(oA3, b3v, 3, obA); STO4(oB3, b3v, 3, obB);
#undef STO4
    } else {
        // ---- stage t2 (conv_out + bo, no relu); wave-local rows ----
        STAGEH(oA0, bo + lg * 4,       0,  false, tws0);
        STAGEH(oA1, bo + 16 + lg * 4,  16, false, tws0);
        STAGEH(oA2, bo + 32 + lg * 4,  32, false, tws0);
        STAGEH(oA3, bo + 48 + lg * 4,  48, false, tws0);
        STAGEH(oB0, bo + lg * 4,       0,  false, tws1);
        STAGEH(oB1, bo + 16 + lg * 4,  16, false, tws1);
        STAGEH(oB2, bo + 32 + lg * 4,  32, false, tws1);
        STAGEH(oB3, bo + 48 + lg * 4,  48, false, tws1);

        // ---- GEMM3: dense 64->32.  C[e][t], 2 subtiles ----
        f32x4 eA0 = {0.f,0.f,0.f,0.f}, eA1 = {0.f,0.f,0.f,0.f};
        f32x4 eB0 = {0.f,0.f,0.f,0.f}, eB1 = {0.f,0.f,0.f,0.f};
        #pragma unroll
        for (int kh = 0; kh < 2; ++kh) {
            f16x8 b0h, b1h, ah;
            HRD(b0h, tws0, kh);
            HRD(b1h, tws1, kh);
            ah = *(const f16x8*)(g_pk + (120 + 0 + kh) * 1024 + la8);
            MFMA1(eA0, ah, b0h); MFMA1(eB0, ah, b1h);
            ah = *(const f16x8*)(g_pk + (120 + 2 + kh) * 1024 + la8);
            MFMA1(eA1, ah, b0h); MFMA1(eB1, ah, b1h);
        }
        const float4 bd0 = *(const float4*)(bd + lg * 4);
        const float4 bd1 = *(const float4*)(bd + 16 + lg * 4);
        const float cI = 1.0f / (float)T_LEN;
        float u0 = (tanhf(eA0[0] + bd0.x) + tanhf(eB0[0] + bd0.x)) * cI;
        float u1 = (tanhf(eA0[1] + bd0.y) + tanhf(eB0[1] + bd0.y)) * cI;
        float u2 = (tanhf(eA0[2] + bd0.z) + tanhf(eB0[2] + bd0.z)) * cI;
        float u3 = (tanhf(eA0[3] + bd0.w) + tanhf(eB0[3] + bd0.w)) * cI;
        float u4 = (tanhf(eA1[0] + bd1.x) + tanhf(eB1[0] + bd1.x)) * cI;
        float u5 = (tanhf(eA1[1] + bd1.y) + tanhf(eB1[1] + bd1.y)) * cI;
        float u6 = (tanhf(eA1[2] + bd1.z) + tanhf(eB1[2] + bd1.z)) * cI;
        float u7 = (tanhf(eA1[3] + bd1.w) + tanhf(eB1[3] + bd1.w)) * cI;
#define RED(U) do { U += __shfl_xor(U, 1); U += __shfl_xor(U, 2);          \
                    U += __shfl_xor(U, 4); U += __shfl_xor(U, 8); } while (0)
        RED(u0); RED(u1); RED(u2); RED(u3);
        RED(u4); RED(u5); RED(u6); RED(u7);
#undef RED
        if (l15 == 0) {
            float* op = outp + b * 32;
            atomicAdd(op + lg * 4 + 0, u0);
            atomicAdd(op + lg * 4 + 1, u1);
            atomicAdd(op + lg * 4 + 2, u2);
            atomicAdd(op + lg * 4 + 3, u3);
            atomicAdd(op + 16 + lg * 4 + 0, u4);
            atomicAdd(op + 16 + lg * 4 + 1, u5);
            atomicAdd(op + 16 + lg * 4 + 2, u6);
            atomicAdd(op + 16 + lg * 4 + 3, u7);
        }
    }
#undef HRD
#undef STAGEH
#undef BRD
#undef LOADA
#undef MFMA1
}

extern "C" void kernel_launch(void* const* d_in, const int* in_sizes, int n_in,
                              void* d_out, int out_size, void* d_ws, size_t ws_size,
                              hipStream_t stream) {
    const float* x     = (const float*)d_in[0];
    const float* gcn_w = (const float*)d_in[1];
    const float* wd    = (const float*)d_in[2];
    const float* bd    = (const float*)d_in[3];
    const float* t1_ws = (const float*)d_in[4];
    const float* t1_bs = (const float*)d_in[5];
    const float* t1_wm = (const float*)d_in[6];
    const float* t1_bm = (const float*)d_in[7];
    const float* t1_wl = (const float*)d_in[8];
    const float* t1_bl = (const float*)d_in[9];
    const float* t1_wo = (const float*)d_in[10];
    const float* t1_bo = (const float*)d_in[11];
    const float* t2_ws = (const float*)d_in[12];
    const float* t2_bs = (const float*)d_in[13];
    const float* t2_wm = (const float*)d_in[14];
    const float* t2_bm = (const float*)d_in[15];
    const float* t2_wl = (const float*)d_in[16];
    const float* t2_bl = (const float*)d_in[17];
    const float* t2_wo = (const float*)d_in[18];
    const float* t2_bo = (const float*)d_in[19];

    float* b0 = (float*)d_ws;                          // [16][64][4096]
    float* b1 = b0 + (size_t)BATCH * 64 * T_LEN;       // [16][64][4096]

    hipMemsetAsync(d_out, 0, (size_t)out_size * sizeof(float), stream);

    k_pack<<<dim3(136), 256, 0, stream>>>(
        t1_ws, t1_wm, t1_wl, t1_wo, t2_ws, t2_wm, t2_wl, t2_wo, wd, gcn_w);

    k_gcn<<<dim3(T_LEN / 64, BATCH), 256, 0, stream>>>(x, b0);

    k_mstcn<false><<<dim3(T_LEN / 128, BATCH), 512, 0, stream>>>(
        b0, t1_bs, t1_bm, t1_bl, t1_bo, 0,
        b1, nullptr, nullptr);

    k_mstcn<true><<<dim3(T_LEN / 128, BATCH), 512, 0, stream>>>(
        b1, t2_bs, t2_bm, t2_bl, t2_bo, 61440,
        nullptr, bd, (float*)d_out);
}